// Round 3
// baseline (393.330 us; speedup 1.0000x reference)
//
#include <hip/hip_runtime.h>
#include <math.h>

#define NQ   4
#define DIM  16
#define NL   6
#define ELEM 4
#define TPB  256

struct Perm { int p[DIM]; };

__host__ __device__ constexpr int cnotp(int c, int t, int idx) {
    return ((idx >> (3 - c)) & 1) ? (idx ^ (1 << (3 - t))) : idx;
}

__host__ __device__ constexpr Perm ring_perm(int r) {
    Perm P{};
    for (int j = 0; j < DIM; ++j) P.p[j] = j;
    for (int i = 0; i < NQ; ++i) {
        Perm Q{};
        for (int j = 0; j < DIM; ++j) Q.p[j] = P.p[cnotp(i, (i + r) % NQ, j)];
        P = Q;
    }
    return P;
}

__device__ inline float4 f4fma(float4 a, float s, float4 c) {
    return make_float4(fmaf(a.x, s, c.x), fmaf(a.y, s, c.y),
                       fmaf(a.z, s, c.z), fmaf(a.w, s, c.w));
}

// ---------------------------------------------------------------------------
// Setup (one block): build U in LDS, then ReM_q = Re(U^dag D_q U) in LDS,
// then the 81x4 contraction tensor C to global ws:
//   out_q = sum_{a,b,c,d in 0..2} C[a,b,c,d][q] * u0_a u1_b u2_c u3_d,
//   u_i = (1, cos x_i, sin x_i).
// ---------------------------------------------------------------------------
__global__ __launch_bounds__(384) void build_all(const float* __restrict__ w,
                                                 float* __restrict__ Cg) {
    __shared__ float Ulds[DIM * DIM * 2];   // [(row*16+col)*2 + {re,im}]
    __shared__ float ReMs[DIM * DIM * 4];   // [(k*16+j)*4 + q]
    const int t = threadIdx.x;

    // Phase 0: threads 0..15 each simulate one column of U.
    if (t < DIM) {
        float cr[DIM], ci[DIM];
        #pragma unroll
        for (int j = 0; j < DIM; ++j) { cr[j] = (j == t) ? 1.0f : 0.0f; ci[j] = 0.0f; }

        #pragma unroll
        for (int l = 0; l < NL; ++l) {
            #pragma unroll
            for (int i = 0; i < NQ; ++i) {
                const float phi = w[(l * NQ + i) * 3 + 0];
                const float th  = w[(l * NQ + i) * 3 + 1];
                const float om  = w[(l * NQ + i) * 3 + 2];
                float ct, st, sp, cp, sm, cm;
                __sincosf(0.5f * th, &st, &ct);
                __sincosf(0.5f * (phi + om), &sp, &cp);
                __sincosf(0.5f * (phi - om), &sm, &cm);
                const float g00r =  cp * ct, g00i = -sp * ct;
                const float g01r = -cm * st, g01i = -sm * st;
                const float g10r =  cm * st, g10i = -sm * st;
                const float g11r =  cp * ct, g11i =  sp * ct;

                const int stride = 1 << (3 - i);
                #pragma unroll
                for (int j = 0; j < DIM; ++j) {
                    if (j & stride) continue;
                    const int j1 = j | stride;
                    const float a0r = cr[j],  a0i = ci[j];
                    const float a1r = cr[j1], a1i = ci[j1];
                    cr[j]  = g00r * a0r - g00i * a0i + g01r * a1r - g01i * a1i;
                    ci[j]  = g00r * a0i + g00i * a0r + g01r * a1i + g01i * a1r;
                    cr[j1] = g10r * a0r - g10i * a0i + g11r * a1r - g11i * a1i;
                    ci[j1] = g10r * a0i + g10i * a0r + g11r * a1i + g11i * a1r;
                }
            }
            constexpr Perm RP[3] = { ring_perm(1), ring_perm(2), ring_perm(3) };
            const Perm& P = RP[l % 3];
            float nr[DIM], ni[DIM];
            #pragma unroll
            for (int j = 0; j < DIM; ++j) { nr[j] = cr[P.p[j]]; ni[j] = ci[P.p[j]]; }
            #pragma unroll
            for (int j = 0; j < DIM; ++j) { cr[j] = nr[j]; ci[j] = ni[j]; }
        }
        #pragma unroll
        for (int j = 0; j < DIM; ++j) {
            Ulds[(j * DIM + t) * 2 + 0] = cr[j];
            Ulds[(j * DIM + t) * 2 + 1] = ci[j];
        }
    }
    __syncthreads();

    // Phase 1: ReM_q[j,k] = sum_m sgn_q(m) * (Ur[m,j]Ur[m,k] + Ui[m,j]Ui[m,k])
    if (t < 256) {
        const int j = t & 15, k = t >> 4;
        float s[4] = {0.f, 0.f, 0.f, 0.f};
        #pragma unroll
        for (int m = 0; m < DIM; ++m) {
            const float rr = Ulds[(m * DIM + j) * 2 + 0] * Ulds[(m * DIM + k) * 2 + 0]
                           + Ulds[(m * DIM + j) * 2 + 1] * Ulds[(m * DIM + k) * 2 + 1];
            #pragma unroll
            for (int q = 0; q < 4; ++q)
                s[q] += ((m >> (3 - q)) & 1) ? -rr : rr;
        }
        #pragma unroll
        for (int q = 0; q < 4; ++q) ReMs[(k * DIM + j) * 4 + q] = s[q];
    }
    __syncthreads();

    // Phase 2: C[r][q], r = a*27+b*9+c*3+d.  Per qubit coeff index e:
    //  e=0 (coeff of 1):    (bj,bk) in {(0,0),(1,1)} weight +1/2
    //  e=1 (coeff of cos):  (0,0)->+1/2, (1,1)->-1/2
    //  e=2 (coeff of sin):  (0,1),(1,0) weight +1/2
    if (t < 324) {
        const int q = t & 3;
        const int r = t >> 2;                 // 0..80
        int e[4];
        e[3] = r % 3; e[2] = (r / 3) % 3; e[1] = (r / 9) % 3; e[0] = r / 27;
        float sum = 0.f;
        #pragma unroll
        for (int o = 0; o < 16; ++o) {
            int j = 0, k = 0; float wgt = 1.f;
            #pragma unroll
            for (int i = 0; i < 4; ++i) {
                const int oi = (o >> i) & 1;
                int bj, bk; float wi;
                if (e[i] == 0)      { bj = oi; bk = oi;     wi = 0.5f; }
                else if (e[i] == 1) { bj = oi; bk = oi;     wi = oi ? -0.5f : 0.5f; }
                else                { bj = oi; bk = oi ^ 1; wi = 0.5f; }
                j |= bj << (3 - i); k |= bk << (3 - i); wgt *= wi;
            }
            sum += wgt * ReMs[(k * DIM + j) * 4 + q];
        }
        Cg[r * 4 + q] = sum;
    }
}

// ---------------------------------------------------------------------------
// Main kernel: out[e][q] = sum C[a,b,c,d][q] u0_a u1_b u2_c u3_d.
// C staged in LDS (1.3 KB), read as wave-uniform broadcast ds_read_b128,
// each 9-float4 block reused across ELEM=4 elements.
// ---------------------------------------------------------------------------
__global__ __launch_bounds__(TPB, 4) void qsim(const float4* __restrict__ x,
                                               const float4* __restrict__ Cg,
                                               float4* __restrict__ out, int T) {
    __shared__ float4 Cs[81];
    const int lt = threadIdx.x;
    if (lt < 81) Cs[lt] = Cg[lt];

    const int tid = blockIdx.x * TPB + lt;
    float C[ELEM][4], S[ELEM][4];
    #pragma unroll
    for (int e = 0; e < ELEM; ++e) {
        const float4 xv = x[tid + e * T];
        __sincosf(xv.x, &S[e][0], &C[e][0]);
        __sincosf(xv.y, &S[e][1], &C[e][1]);
        __sincosf(xv.z, &S[e][2], &C[e][2]);
        __sincosf(xv.w, &S[e][3], &C[e][3]);
    }
    __syncthreads();

    float4 acc[ELEM], Ga[ELEM];
    #pragma unroll
    for (int a = 0; a < 3; ++a) {
        #pragma unroll
        for (int b = 0; b < 3; ++b) {
            float4 L[9];
            #pragma unroll
            for (int m = 0; m < 9; ++m) L[m] = Cs[(a * 3 + b) * 9 + m];
            #pragma unroll
            for (int e = 0; e < ELEM; ++e) {
                // contract qubit3 (d) then qubit2 (c)
                float4 F  = f4fma(L[2], S[e][3], f4fma(L[1], C[e][3], L[0]));
                float4 E1 = f4fma(L[5], S[e][3], f4fma(L[4], C[e][3], L[3]));
                F = f4fma(E1, C[e][2], F);
                float4 E2 = f4fma(L[8], S[e][3], f4fma(L[7], C[e][3], L[6]));
                F = f4fma(E2, S[e][2], F);
                // contract qubit1 (b)
                if (b == 0)      Ga[e] = F;
                else if (b == 1) Ga[e] = f4fma(F, C[e][1], Ga[e]);
                else             Ga[e] = f4fma(F, S[e][1], Ga[e]);
            }
        }
        #pragma unroll
        for (int e = 0; e < ELEM; ++e) {      // contract qubit0 (a)
            if (a == 0)      acc[e] = Ga[e];
            else if (a == 1) acc[e] = f4fma(Ga[e], C[e][0], acc[e]);
            else             acc[e] = f4fma(Ga[e], S[e][0], acc[e]);
        }
    }

    #pragma unroll
    for (int e = 0; e < ELEM; ++e)
        out[tid + e * T] = acc[e];
}

extern "C" void kernel_launch(void* const* d_in, const int* in_sizes, int n_in,
                              void* d_out, int out_size, void* d_ws, size_t ws_size,
                              hipStream_t stream) {
    const float* x = (const float*)d_in[0];   // (B, 4) f32
    const float* w = (const float*)d_in[1];   // (6, 4, 3) f32
    float* Cg = (float*)d_ws;                 // 81 * float4 = 1296 B
    const int B = in_sizes[0] / NQ;
    const int T = B / ELEM;

    build_all<<<1, 384, 0, stream>>>(w, Cg);
    qsim<<<(T + TPB - 1) / TPB, TPB, 0, stream>>>((const float4*)x, (const float4*)Cg,
                                                  (float4*)d_out, T);
}

// Round 4
// 51.709 us; speedup vs baseline: 7.6065x; 7.6065x over previous
//
#include <hip/hip_runtime.h>
#include <math.h>

#define NQ   4
#define DIM  16
#define NL   6
#define ELEM 4
#define TPB  256

struct Perm { int p[DIM]; };

__host__ __device__ constexpr int cnotp(int c, int t, int idx) {
    return ((idx >> (3 - c)) & 1) ? (idx ^ (1 << (3 - t))) : idx;
}

__host__ __device__ constexpr Perm ring_perm(int r) {
    Perm P{};
    for (int j = 0; j < DIM; ++j) P.p[j] = j;
    for (int i = 0; i < NQ; ++i) {
        Perm Q{};
        for (int j = 0; j < DIM; ++j) Q.p[j] = P.p[cnotp(i, (i + r) % NQ, j)];
        P = Q;
    }
    return P;
}

__device__ inline float4 f4fma(float4 a, float s, float4 c) {
    return make_float4(fmaf(a.x, s, c.x), fmaf(a.y, s, c.y),
                       fmaf(a.z, s, c.z), fmaf(a.w, s, c.w));
}

// ---------------------------------------------------------------------------
// Setup (one block): build U in LDS, then ReM_q = Re(U^dag D_q U) in LDS,
// then the 81x4 contraction tensor C to global ws:
//   out_q = sum_{a,b,c,d in 0..2} C[a,b,c,d][q] * u0_a u1_b u2_c u3_d,
//   u_i = (1, cos x_i, sin x_i).
// ---------------------------------------------------------------------------
__global__ __launch_bounds__(384) void build_all(const float* __restrict__ w,
                                                 float* __restrict__ Cg) {
    __shared__ float Ulds[DIM * DIM * 2];   // [(row*16+col)*2 + {re,im}]
    __shared__ float ReMs[DIM * DIM * 4];   // [(k*16+j)*4 + q]
    const int t = threadIdx.x;

    // Phase 0: threads 0..15 each simulate one column of U.
    if (t < DIM) {
        float cr[DIM], ci[DIM];
        #pragma unroll
        for (int j = 0; j < DIM; ++j) { cr[j] = (j == t) ? 1.0f : 0.0f; ci[j] = 0.0f; }

        #pragma unroll
        for (int l = 0; l < NL; ++l) {
            #pragma unroll
            for (int i = 0; i < NQ; ++i) {
                const float phi = w[(l * NQ + i) * 3 + 0];
                const float th  = w[(l * NQ + i) * 3 + 1];
                const float om  = w[(l * NQ + i) * 3 + 2];
                float ct, st, sp, cp, sm, cm;
                __sincosf(0.5f * th, &st, &ct);
                __sincosf(0.5f * (phi + om), &sp, &cp);
                __sincosf(0.5f * (phi - om), &sm, &cm);
                const float g00r =  cp * ct, g00i = -sp * ct;
                const float g01r = -cm * st, g01i = -sm * st;
                const float g10r =  cm * st, g10i = -sm * st;
                const float g11r =  cp * ct, g11i =  sp * ct;

                const int stride = 1 << (3 - i);
                #pragma unroll
                for (int j = 0; j < DIM; ++j) {
                    if (j & stride) continue;
                    const int j1 = j | stride;
                    const float a0r = cr[j],  a0i = ci[j];
                    const float a1r = cr[j1], a1i = ci[j1];
                    cr[j]  = g00r * a0r - g00i * a0i + g01r * a1r - g01i * a1i;
                    ci[j]  = g00r * a0i + g00i * a0r + g01r * a1i + g01i * a1r;
                    cr[j1] = g10r * a0r - g10i * a0i + g11r * a1r - g11i * a1i;
                    ci[j1] = g10r * a0i + g10i * a0r + g11r * a1i + g11i * a1r;
                }
            }
            constexpr Perm RP[3] = { ring_perm(1), ring_perm(2), ring_perm(3) };
            const Perm& P = RP[l % 3];
            float nr[DIM], ni[DIM];
            #pragma unroll
            for (int j = 0; j < DIM; ++j) { nr[j] = cr[P.p[j]]; ni[j] = ci[P.p[j]]; }
            #pragma unroll
            for (int j = 0; j < DIM; ++j) { cr[j] = nr[j]; ci[j] = ni[j]; }
        }
        #pragma unroll
        for (int j = 0; j < DIM; ++j) {
            Ulds[(j * DIM + t) * 2 + 0] = cr[j];
            Ulds[(j * DIM + t) * 2 + 1] = ci[j];
        }
    }
    __syncthreads();

    // Phase 1: ReM_q[j,k] = sum_m sgn_q(m) * (Ur[m,j]Ur[m,k] + Ui[m,j]Ui[m,k])
    if (t < 256) {
        const int j = t & 15, k = t >> 4;
        float s[4] = {0.f, 0.f, 0.f, 0.f};
        #pragma unroll
        for (int m = 0; m < DIM; ++m) {
            const float rr = Ulds[(m * DIM + j) * 2 + 0] * Ulds[(m * DIM + k) * 2 + 0]
                           + Ulds[(m * DIM + j) * 2 + 1] * Ulds[(m * DIM + k) * 2 + 1];
            #pragma unroll
            for (int q = 0; q < 4; ++q)
                s[q] += ((m >> (3 - q)) & 1) ? -rr : rr;
        }
        #pragma unroll
        for (int q = 0; q < 4; ++q) ReMs[(k * DIM + j) * 4 + q] = s[q];
    }
    __syncthreads();

    // Phase 2: C[r][q], r = a*27+b*9+c*3+d.  Per qubit coeff index e:
    //  e=0 (coeff of 1):    (bj,bk) in {(0,0),(1,1)} weight +1/2
    //  e=1 (coeff of cos):  (0,0)->+1/2, (1,1)->-1/2
    //  e=2 (coeff of sin):  (0,1),(1,0) weight +1/2
    if (t < 324) {
        const int q = t & 3;
        const int r = t >> 2;                 // 0..80
        int e[4];
        e[3] = r % 3; e[2] = (r / 3) % 3; e[1] = (r / 9) % 3; e[0] = r / 27;
        float sum = 0.f;
        #pragma unroll
        for (int o = 0; o < 16; ++o) {
            int j = 0, k = 0; float wgt = 1.f;
            #pragma unroll
            for (int i = 0; i < 4; ++i) {
                const int oi = (o >> i) & 1;
                int bj, bk; float wi;
                if (e[i] == 0)      { bj = oi; bk = oi;     wi = 0.5f; }
                else if (e[i] == 1) { bj = oi; bk = oi;     wi = oi ? -0.5f : 0.5f; }
                else                { bj = oi; bk = oi ^ 1; wi = 0.5f; }
                j |= bj << (3 - i); k |= bk << (3 - i); wgt *= wi;
            }
            sum += wgt * ReMs[(k * DIM + j) * 4 + q];
        }
        Cg[r * 4 + q] = sum;
    }
}

// ---------------------------------------------------------------------------
// Main kernel: out[e][q] = sum C[a,b,c,d][q] u0_a u1_b u2_c u3_d.
// C staged in LDS (1.3 KB), read as wave-uniform broadcast ds_read_b128,
// each 9-float4 block reused across ELEM=4 elements.
// NOTE: no min-waves arg in __launch_bounds__ — round 3 showed that capping
// VGPRs at 64 spills ~1.2 GB of scratch traffic (needs ~120 live VGPRs).
// ---------------------------------------------------------------------------
__global__ __launch_bounds__(TPB) void qsim(const float4* __restrict__ x,
                                            const float4* __restrict__ Cg,
                                            float4* __restrict__ out, int T) {
    __shared__ float4 Cs[81];
    const int lt = threadIdx.x;
    if (lt < 81) Cs[lt] = Cg[lt];

    const int tid = blockIdx.x * TPB + lt;
    float C[ELEM][4], S[ELEM][4];
    #pragma unroll
    for (int e = 0; e < ELEM; ++e) {
        const float4 xv = x[tid + e * T];
        __sincosf(xv.x, &S[e][0], &C[e][0]);
        __sincosf(xv.y, &S[e][1], &C[e][1]);
        __sincosf(xv.z, &S[e][2], &C[e][2]);
        __sincosf(xv.w, &S[e][3], &C[e][3]);
    }
    __syncthreads();

    float4 acc[ELEM], Ga[ELEM];
    #pragma unroll
    for (int a = 0; a < 3; ++a) {
        #pragma unroll
        for (int b = 0; b < 3; ++b) {
            float4 L[9];
            #pragma unroll
            for (int m = 0; m < 9; ++m) L[m] = Cs[(a * 3 + b) * 9 + m];
            #pragma unroll
            for (int e = 0; e < ELEM; ++e) {
                // contract qubit3 (d) then qubit2 (c)
                float4 F  = f4fma(L[2], S[e][3], f4fma(L[1], C[e][3], L[0]));
                float4 E1 = f4fma(L[5], S[e][3], f4fma(L[4], C[e][3], L[3]));
                F = f4fma(E1, C[e][2], F);
                float4 E2 = f4fma(L[8], S[e][3], f4fma(L[7], C[e][3], L[6]));
                F = f4fma(E2, S[e][2], F);
                // contract qubit1 (b)
                if (b == 0)      Ga[e] = F;
                else if (b == 1) Ga[e] = f4fma(F, C[e][1], Ga[e]);
                else             Ga[e] = f4fma(F, S[e][1], Ga[e]);
            }
        }
        #pragma unroll
        for (int e = 0; e < ELEM; ++e) {      // contract qubit0 (a)
            if (a == 0)      acc[e] = Ga[e];
            else if (a == 1) acc[e] = f4fma(Ga[e], C[e][0], acc[e]);
            else             acc[e] = f4fma(Ga[e], S[e][0], acc[e]);
        }
    }

    #pragma unroll
    for (int e = 0; e < ELEM; ++e)
        out[tid + e * T] = acc[e];
}

extern "C" void kernel_launch(void* const* d_in, const int* in_sizes, int n_in,
                              void* d_out, int out_size, void* d_ws, size_t ws_size,
                              hipStream_t stream) {
    const float* x = (const float*)d_in[0];   // (B, 4) f32
    const float* w = (const float*)d_in[1];   // (6, 4, 3) f32
    float* Cg = (float*)d_ws;                 // 81 * float4 = 1296 B
    const int B = in_sizes[0] / NQ;
    const int T = B / ELEM;

    build_all<<<1, 384, 0, stream>>>(w, Cg);
    qsim<<<(T + TPB - 1) / TPB, TPB, 0, stream>>>((const float4*)x, (const float4*)Cg,
                                                  (float4*)d_out, T);
}

// Round 5
// 32.848 us; speedup vs baseline: 11.9742x; 1.5742x over previous
//
#include <hip/hip_runtime.h>
#include <math.h>

#define NQ   4
#define DIM  16
#define NL   6
#define ELEM 4
#define TPB  256

struct Perm { int p[DIM]; };

__host__ __device__ constexpr int cnotp(int c, int t, int idx) {
    return ((idx >> (3 - c)) & 1) ? (idx ^ (1 << (3 - t))) : idx;
}

__host__ __device__ constexpr Perm ring_perm(int r) {
    Perm P{};
    for (int j = 0; j < DIM; ++j) P.p[j] = j;
    for (int i = 0; i < NQ; ++i) {
        Perm Q{};
        for (int j = 0; j < DIM; ++j) Q.p[j] = P.p[cnotp(i, (i + r) % NQ, j)];
        P = Q;
    }
    return P;
}

__device__ inline float4 f4fma(float4 a, float s, float4 c) {
    return make_float4(fmaf(a.x, s, c.x), fmaf(a.y, s, c.y),
                       fmaf(a.z, s, c.z), fmaf(a.w, s, c.w));
}

// ---------------------------------------------------------------------------
// Setup (one block): build U in LDS, then ReM_q = Re(U^dag D_q U), then the
// 81x4 contraction tensor C to global ws:
//   out_q = sum_{a,b,c,d in 0..2} C[a,b,c,d][q] * u0_a u1_b u2_c u3_d,
//   u_i = (1, cos x_i, sin x_i).
// ---------------------------------------------------------------------------
__global__ __launch_bounds__(384) void build_all(const float* __restrict__ w,
                                                 float* __restrict__ Cg) {
    __shared__ float Ulds[DIM * DIM * 2];   // [(row*16+col)*2 + {re,im}]
    __shared__ float ReMs[DIM * DIM * 4];   // [(k*16+j)*4 + q]
    const int t = threadIdx.x;

    if (t < DIM) {
        float cr[DIM], ci[DIM];
        #pragma unroll
        for (int j = 0; j < DIM; ++j) { cr[j] = (j == t) ? 1.0f : 0.0f; ci[j] = 0.0f; }

        #pragma unroll
        for (int l = 0; l < NL; ++l) {
            #pragma unroll
            for (int i = 0; i < NQ; ++i) {
                const float phi = w[(l * NQ + i) * 3 + 0];
                const float th  = w[(l * NQ + i) * 3 + 1];
                const float om  = w[(l * NQ + i) * 3 + 2];
                float ct, st, sp, cp, sm, cm;
                __sincosf(0.5f * th, &st, &ct);
                __sincosf(0.5f * (phi + om), &sp, &cp);
                __sincosf(0.5f * (phi - om), &sm, &cm);
                const float g00r =  cp * ct, g00i = -sp * ct;
                const float g01r = -cm * st, g01i = -sm * st;
                const float g10r =  cm * st, g10i = -sm * st;
                const float g11r =  cp * ct, g11i =  sp * ct;

                const int stride = 1 << (3 - i);
                #pragma unroll
                for (int j = 0; j < DIM; ++j) {
                    if (j & stride) continue;
                    const int j1 = j | stride;
                    const float a0r = cr[j],  a0i = ci[j];
                    const float a1r = cr[j1], a1i = ci[j1];
                    cr[j]  = g00r * a0r - g00i * a0i + g01r * a1r - g01i * a1i;
                    ci[j]  = g00r * a0i + g00i * a0r + g01r * a1i + g01i * a1r;
                    cr[j1] = g10r * a0r - g10i * a0i + g11r * a1r - g11i * a1i;
                    ci[j1] = g10r * a0i + g10i * a0r + g11r * a1i + g11i * a1r;
                }
            }
            constexpr Perm RP[3] = { ring_perm(1), ring_perm(2), ring_perm(3) };
            const Perm& P = RP[l % 3];
            float nr[DIM], ni[DIM];
            #pragma unroll
            for (int j = 0; j < DIM; ++j) { nr[j] = cr[P.p[j]]; ni[j] = ci[P.p[j]]; }
            #pragma unroll
            for (int j = 0; j < DIM; ++j) { cr[j] = nr[j]; ci[j] = ni[j]; }
        }
        #pragma unroll
        for (int j = 0; j < DIM; ++j) {
            Ulds[(j * DIM + t) * 2 + 0] = cr[j];
            Ulds[(j * DIM + t) * 2 + 1] = ci[j];
        }
    }
    __syncthreads();

    if (t < 256) {
        const int j = t & 15, k = t >> 4;
        float s[4] = {0.f, 0.f, 0.f, 0.f};
        #pragma unroll
        for (int m = 0; m < DIM; ++m) {
            const float rr = Ulds[(m * DIM + j) * 2 + 0] * Ulds[(m * DIM + k) * 2 + 0]
                           + Ulds[(m * DIM + j) * 2 + 1] * Ulds[(m * DIM + k) * 2 + 1];
            #pragma unroll
            for (int q = 0; q < 4; ++q)
                s[q] += ((m >> (3 - q)) & 1) ? -rr : rr;
        }
        #pragma unroll
        for (int q = 0; q < 4; ++q) ReMs[(k * DIM + j) * 4 + q] = s[q];
    }
    __syncthreads();

    if (t < 324) {
        const int q = t & 3;
        const int r = t >> 2;                 // 0..80
        int e[4];
        e[3] = r % 3; e[2] = (r / 3) % 3; e[1] = (r / 9) % 3; e[0] = r / 27;
        float sum = 0.f;
        #pragma unroll
        for (int o = 0; o < 16; ++o) {
            int j = 0, k = 0; float wgt = 1.f;
            #pragma unroll
            for (int i = 0; i < 4; ++i) {
                const int oi = (o >> i) & 1;
                int bj, bk; float wi;
                if (e[i] == 0)      { bj = oi; bk = oi;     wi = 0.5f; }
                else if (e[i] == 1) { bj = oi; bk = oi;     wi = oi ? -0.5f : 0.5f; }
                else                { bj = oi; bk = oi ^ 1; wi = 0.5f; }
                j |= bj << (3 - i); k |= bk << (3 - i); wgt *= wi;
            }
            sum += wgt * ReMs[(k * DIM + j) * 4 + q];
        }
        Cg[r * 4 + q] = sum;
    }
}

// ---------------------------------------------------------------------------
// Main kernel. Outer contraction levels (a,b) are RUNTIME loops (unroll 1):
// round 4 showed full unroll hoists all 81 ds_read_b128 -> 256 VGPR + spill.
// With unroll 1 only one L[9] block (36 VGPR) is live; qubit-0/1 weights are
// register cndmask selects. Live set ~115 VGPR -> 4 waves/SIMD, no spill.
// ---------------------------------------------------------------------------
__global__ __launch_bounds__(TPB) void qsim(const float4* __restrict__ x,
                                            const float4* __restrict__ Cg,
                                            float4* __restrict__ out, int T) {
    __shared__ float4 Cs[81];
    const int lt = threadIdx.x;
    if (lt < 81) Cs[lt] = Cg[lt];

    const int tid = blockIdx.x * TPB + lt;
    float C[ELEM][4], S[ELEM][4];
    #pragma unroll
    for (int e = 0; e < ELEM; ++e) {
        const float4 xv = x[tid + e * T];
        __sincosf(xv.x, &S[e][0], &C[e][0]);
        __sincosf(xv.y, &S[e][1], &C[e][1]);
        __sincosf(xv.z, &S[e][2], &C[e][2]);
        __sincosf(xv.w, &S[e][3], &C[e][3]);
    }
    __syncthreads();

    float4 acc[ELEM];
    #pragma unroll
    for (int e = 0; e < ELEM; ++e) acc[e] = make_float4(0.f, 0.f, 0.f, 0.f);

    #pragma unroll 1
    for (int a = 0; a < 3; ++a) {
        float4 Ga[ELEM];
        #pragma unroll
        for (int e = 0; e < ELEM; ++e) Ga[e] = make_float4(0.f, 0.f, 0.f, 0.f);

        #pragma unroll 1
        for (int b = 0; b < 3; ++b) {
            float4 L[9];
            #pragma unroll
            for (int m = 0; m < 9; ++m) L[m] = Cs[(a * 3 + b) * 9 + m];

            #pragma unroll
            for (int e = 0; e < ELEM; ++e) {
                const float wb = (b == 0) ? 1.0f : ((b == 1) ? C[e][1] : S[e][1]);
                // contract qubit3 (d) then qubit2 (c)
                float4 F  = f4fma(L[2], S[e][3], f4fma(L[1], C[e][3], L[0]));
                float4 E1 = f4fma(L[5], S[e][3], f4fma(L[4], C[e][3], L[3]));
                F = f4fma(E1, C[e][2], F);
                float4 E2 = f4fma(L[8], S[e][3], f4fma(L[7], C[e][3], L[6]));
                F = f4fma(E2, S[e][2], F);
                Ga[e] = f4fma(F, wb, Ga[e]);
            }
        }
        #pragma unroll
        for (int e = 0; e < ELEM; ++e) {
            const float wa = (a == 0) ? 1.0f : ((a == 1) ? C[e][0] : S[e][0]);
            acc[e] = f4fma(Ga[e], wa, acc[e]);
        }
    }

    #pragma unroll
    for (int e = 0; e < ELEM; ++e)
        out[tid + e * T] = acc[e];
}

extern "C" void kernel_launch(void* const* d_in, const int* in_sizes, int n_in,
                              void* d_out, int out_size, void* d_ws, size_t ws_size,
                              hipStream_t stream) {
    const float* x = (const float*)d_in[0];   // (B, 4) f32
    const float* w = (const float*)d_in[1];   // (6, 4, 3) f32
    float* Cg = (float*)d_ws;                 // 81 * float4 = 1296 B
    const int B = in_sizes[0] / NQ;
    const int T = B / ELEM;

    build_all<<<1, 384, 0, stream>>>(w, Cg);
    qsim<<<(T + TPB - 1) / TPB, TPB, 0, stream>>>((const float4*)x, (const float4*)Cg,
                                                  (float4*)d_out, T);
}

// Round 6
// 32.143 us; speedup vs baseline: 12.2368x; 1.0219x over previous
//
#include <hip/hip_runtime.h>
#include <math.h>

#define NQ   4
#define DIM  16
#define NL   6
#define ELEM 4
#define TPB  256

#define INV2PI 0.15915494309189535f

// Hardware trig: v_sin_f32 / v_cos_f32 take input in revolutions.
// Value-returning -> no address-taken locals -> no private-memory allocation.
__device__ inline float hsin(float rad) { return __builtin_amdgcn_sinf(rad * INV2PI); }
__device__ inline float hcos(float rad) { return __builtin_amdgcn_cosf(rad * INV2PI); }

struct Perm { int p[DIM]; };

__host__ __device__ constexpr int cnotp(int c, int t, int idx) {
    return ((idx >> (3 - c)) & 1) ? (idx ^ (1 << (3 - t))) : idx;
}

__host__ __device__ constexpr Perm ring_perm(int r) {
    Perm P{};
    for (int j = 0; j < DIM; ++j) P.p[j] = j;
    for (int i = 0; i < NQ; ++i) {
        Perm Q{};
        for (int j = 0; j < DIM; ++j) Q.p[j] = P.p[cnotp(i, (i + r) % NQ, j)];
        P = Q;
    }
    return P;
}

__device__ inline float4 f4fma(float4 a, float s, float4 c) {
    return make_float4(fmaf(a.x, s, c.x), fmaf(a.y, s, c.y),
                       fmaf(a.z, s, c.z), fmaf(a.w, s, c.w));
}

// ---------------------------------------------------------------------------
// Setup (one block): build U in LDS, then ReM_q = Re(U^dag D_q U), then the
// 81x4 contraction tensor C to global ws:
//   out_q = sum_{a,b,c,d in 0..2} C[a,b,c,d][q] * u0_a u1_b u2_c u3_d,
//   u_i = (1, cos x_i, sin x_i).
// ---------------------------------------------------------------------------
__global__ __launch_bounds__(384) void build_all(const float* __restrict__ w,
                                                 float* __restrict__ Cg) {
    __shared__ float Ulds[DIM * DIM * 2];   // [(row*16+col)*2 + {re,im}]
    __shared__ float ReMs[DIM * DIM * 4];   // [(k*16+j)*4 + q]
    const int t = threadIdx.x;

    if (t < DIM) {
        float cr[DIM], ci[DIM];
        #pragma unroll
        for (int j = 0; j < DIM; ++j) { cr[j] = (j == t) ? 1.0f : 0.0f; ci[j] = 0.0f; }

        #pragma unroll
        for (int l = 0; l < NL; ++l) {
            #pragma unroll
            for (int i = 0; i < NQ; ++i) {
                const float phi = w[(l * NQ + i) * 3 + 0];
                const float th  = w[(l * NQ + i) * 3 + 1];
                const float om  = w[(l * NQ + i) * 3 + 2];
                const float ct = hcos(0.5f * th),          st = hsin(0.5f * th);
                const float cp = hcos(0.5f * (phi + om)),  sp = hsin(0.5f * (phi + om));
                const float cm = hcos(0.5f * (phi - om)),  sm = hsin(0.5f * (phi - om));
                const float g00r =  cp * ct, g00i = -sp * ct;
                const float g01r = -cm * st, g01i = -sm * st;
                const float g10r =  cm * st, g10i = -sm * st;
                const float g11r =  cp * ct, g11i =  sp * ct;

                const int stride = 1 << (3 - i);
                #pragma unroll
                for (int j = 0; j < DIM; ++j) {
                    if (j & stride) continue;
                    const int j1 = j | stride;
                    const float a0r = cr[j],  a0i = ci[j];
                    const float a1r = cr[j1], a1i = ci[j1];
                    cr[j]  = g00r * a0r - g00i * a0i + g01r * a1r - g01i * a1i;
                    ci[j]  = g00r * a0i + g00i * a0r + g01r * a1i + g01i * a1r;
                    cr[j1] = g10r * a0r - g10i * a0i + g11r * a1r - g11i * a1i;
                    ci[j1] = g10r * a0i + g10i * a0r + g11r * a1i + g11i * a1r;
                }
            }
            constexpr Perm RP[3] = { ring_perm(1), ring_perm(2), ring_perm(3) };
            const Perm& P = RP[l % 3];
            float nr[DIM], ni[DIM];
            #pragma unroll
            for (int j = 0; j < DIM; ++j) { nr[j] = cr[P.p[j]]; ni[j] = ci[P.p[j]]; }
            #pragma unroll
            for (int j = 0; j < DIM; ++j) { cr[j] = nr[j]; ci[j] = ni[j]; }
        }
        #pragma unroll
        for (int j = 0; j < DIM; ++j) {
            Ulds[(j * DIM + t) * 2 + 0] = cr[j];
            Ulds[(j * DIM + t) * 2 + 1] = ci[j];
        }
    }
    __syncthreads();

    if (t < 256) {
        const int j = t & 15, k = t >> 4;
        float s[4] = {0.f, 0.f, 0.f, 0.f};
        #pragma unroll
        for (int m = 0; m < DIM; ++m) {
            const float rr = Ulds[(m * DIM + j) * 2 + 0] * Ulds[(m * DIM + k) * 2 + 0]
                           + Ulds[(m * DIM + j) * 2 + 1] * Ulds[(m * DIM + k) * 2 + 1];
            #pragma unroll
            for (int q = 0; q < 4; ++q)
                s[q] += ((m >> (3 - q)) & 1) ? -rr : rr;
        }
        #pragma unroll
        for (int q = 0; q < 4; ++q) ReMs[(k * DIM + j) * 4 + q] = s[q];
    }
    __syncthreads();

    if (t < 324) {
        const int q = t & 3;
        const int r = t >> 2;                 // 0..80
        int e[4];
        e[3] = r % 3; e[2] = (r / 3) % 3; e[1] = (r / 9) % 3; e[0] = r / 27;
        float sum = 0.f;
        #pragma unroll
        for (int o = 0; o < 16; ++o) {
            int j = 0, k = 0; float wgt = 1.f;
            #pragma unroll
            for (int i = 0; i < 4; ++i) {
                const int oi = (o >> i) & 1;
                int bj, bk; float wi;
                if (e[i] == 0)      { bj = oi; bk = oi;     wi = 0.5f; }
                else if (e[i] == 1) { bj = oi; bk = oi;     wi = oi ? -0.5f : 0.5f; }
                else                { bj = oi; bk = oi ^ 1; wi = 0.5f; }
                j |= bj << (3 - i); k |= bk << (3 - i); wgt *= wi;
            }
            sum += wgt * ReMs[(k * DIM + j) * 4 + q];
        }
        Cg[r * 4 + q] = sum;
    }
}

// ---------------------------------------------------------------------------
// Main kernel. Round-5 lesson: __sincosf's pointer args made the trig arrays
// address-taken -> private memory -> scratch reads in the hot loop. Now all
// trig is value-returning hardware sin/cos; no local ever has its address
// taken, so everything lives in registers (~100 VGPR, 5 waves/SIMD).
// Outer (a,b) levels stay runtime loops (round-4 lesson: full unroll hoists
// all 81 ds_read_b128 -> 256 VGPR + spill). Ga folded away via wab = wa*wb.
// ---------------------------------------------------------------------------
__global__ __launch_bounds__(TPB) void qsim(const float4* __restrict__ x,
                                            const float4* __restrict__ Cg,
                                            float4* __restrict__ out, int T) {
    __shared__ float4 Cs[81];
    const int lt = threadIdx.x;
    if (lt < 81) Cs[lt] = Cg[lt];

    const int tid = blockIdx.x * TPB + lt;
    float C[ELEM][4], S[ELEM][4];
    #pragma unroll
    for (int e = 0; e < ELEM; ++e) {
        const float4 xv = x[tid + e * T];
        C[e][0] = hcos(xv.x); S[e][0] = hsin(xv.x);
        C[e][1] = hcos(xv.y); S[e][1] = hsin(xv.y);
        C[e][2] = hcos(xv.z); S[e][2] = hsin(xv.z);
        C[e][3] = hcos(xv.w); S[e][3] = hsin(xv.w);
    }
    __syncthreads();

    float4 acc[ELEM];
    #pragma unroll
    for (int e = 0; e < ELEM; ++e) acc[e] = make_float4(0.f, 0.f, 0.f, 0.f);

    #pragma unroll 1
    for (int a = 0; a < 3; ++a) {
        #pragma unroll 1
        for (int b = 0; b < 3; ++b) {
            float4 L[9];
            #pragma unroll
            for (int m = 0; m < 9; ++m) L[m] = Cs[(a * 3 + b) * 9 + m];

            #pragma unroll
            for (int e = 0; e < ELEM; ++e) {
                const float wa = (a == 0) ? 1.0f : ((a == 1) ? C[e][0] : S[e][0]);
                const float wb = (b == 0) ? 1.0f : ((b == 1) ? C[e][1] : S[e][1]);
                const float wab = wa * wb;
                // contract qubit3 (d) then qubit2 (c)
                float4 F  = f4fma(L[2], S[e][3], f4fma(L[1], C[e][3], L[0]));
                float4 E1 = f4fma(L[5], S[e][3], f4fma(L[4], C[e][3], L[3]));
                F = f4fma(E1, C[e][2], F);
                float4 E2 = f4fma(L[8], S[e][3], f4fma(L[7], C[e][3], L[6]));
                F = f4fma(E2, S[e][2], F);
                acc[e] = f4fma(F, wab, acc[e]);
            }
        }
    }

    #pragma unroll
    for (int e = 0; e < ELEM; ++e)
        out[tid + e * T] = acc[e];
}

extern "C" void kernel_launch(void* const* d_in, const int* in_sizes, int n_in,
                              void* d_out, int out_size, void* d_ws, size_t ws_size,
                              hipStream_t stream) {
    const float* x = (const float*)d_in[0];   // (B, 4) f32
    const float* w = (const float*)d_in[1];   // (6, 4, 3) f32
    float* Cg = (float*)d_ws;                 // 81 * float4 = 1296 B
    const int B = in_sizes[0] / NQ;
    const int T = B / ELEM;

    build_all<<<1, 384, 0, stream>>>(w, Cg);
    qsim<<<(T + TPB - 1) / TPB, TPB, 0, stream>>>((const float4*)x, (const float4*)Cg,
                                                  (float4*)d_out, T);
}